// Round 1
// baseline (8106.380 us; speedup 1.0000x reference)
//
#include <hip/hip_runtime.h>
#include <hip/hip_bf16.h>

// 2-layer LSTM, B=64, F=128, T=1024, H=512. Output = h_T of layer 1 (64x512 fp32).
// R5: batch-grouped sub-barriers. The LSTM recurrence is batch-diagonal (gates[b]
// depend only on h[b]), so the grid splits into 4 independent groups of 16 batches.
// Each group: 64 WGs (32 layer-0 + 32 layer-1), weights fully register-resident
// (same per-thread frag budget as R4: each wave owns its own col-quad).
//   - barrier fan-in 256 -> 64, four decoupled barriers (no cross-group jitter)
//   - h broadcast 26MB -> 6.6MB/step (each WG reads only its 16-batch slice)
//   - g = blockIdx&3 => group confined to XCDs {g, g+4} under %8 round-robin;
//     acquire buffer_inv blast radius = own group's two L2s only
//   - barrier split arrive/wait; layer-0 hides next-step x-GEMM under the wait
//   - flags packed 4B apart: one wave polls 64 flags in one coalesced load
//   - sG per-wave-private => no mid-iteration __syncthreads; stride 72 (2-way, free)
// Protocol per R2/R4: 4-gen h rotation, relaxed agent sc0sc1 publish, syncthreads
// vmcnt-drain before flag store, flag store+poll, wave0 acquire fence (buffer_inv).

#define B_ 64
#define F_ 128
#define T_ 1024
#define H_ 512
#define NWG 256

typedef __bf16 bf16x8 __attribute__((ext_vector_type(8)));
typedef float f32x4 __attribute__((ext_vector_type(4)));

__device__ __forceinline__ float sigm(float x) { return 1.0f / (1.0f + __expf(-x)); }
__device__ __forceinline__ float tanh_fast(float x) { return 1.0f - 2.0f / (__expf(2.0f * x) + 1.0f); }

// x (B,F,T) fp32 -> xT (T,B,F) bf16
__global__ __launch_bounds__(256) void transpose_x_kernel(const float* __restrict__ x,
                                                          __bf16* __restrict__ xT) {
  __shared__ float tile[F_][65];
  const int bb = blockIdx.x >> 4;
  const int tt = blockIdx.x & 15;
  const int tid = threadIdx.x;
  const int tl = tid & 63;
  const int f0 = tid >> 6;
  for (int fo = 0; fo < F_; fo += 4) {
    int f = fo + f0;
    tile[f][tl] = x[((size_t)bb * F_ + f) * T_ + tt * 64 + tl];
  }
  __syncthreads();
  const int fw = tid & 127;
  const int tg = tid >> 7;
  for (int to = 0; to < 64; to += 2) {
    int t = to + tg;
    xT[((size_t)(tt * 64 + t) * B_ + bb) * F_ + fw] = (__bf16)tile[fw][t];
  }
}

// Group barrier (64 WGs). arrive: drain publishes (syncthreads emits s_waitcnt
// vmcnt(0) before s_barrier, so all stores are acked) then post monotone counter.
__device__ __forceinline__ void barrier_arrive(unsigned* gfl, int wgl, int tid, unsigned tgt) {
  __syncthreads();
  if (tid == 0)
    __hip_atomic_store(&gfl[wgl], tgt, __ATOMIC_RELAXED, __HIP_MEMORY_SCOPE_AGENT);
}

// wait: wave 0 polls all 64 group flags (4B each -> one coalesced load spanning
// 4 lines), then one acquire fence per WG drops stale L1/L2 lines before h reads.
__device__ __forceinline__ void barrier_wait(unsigned* gfl, int tid, unsigned tgt) {
  if (tid < 64)
    while (__hip_atomic_load(&gfl[tid], __ATOMIC_RELAXED, __HIP_MEMORY_SCOPE_AGENT) < tgt)
      __builtin_amdgcn_s_sleep(1);
  __syncthreads();   // all flags observed by wave 0
  if (tid < 64)
    __builtin_amdgcn_fence(__ATOMIC_ACQUIRE, "agent");
  __syncthreads();   // no wave issues loads before the inv
}

__global__ __launch_bounds__(256, 2) void lstm_persistent(
    const __bf16* __restrict__ xT,
    const float* __restrict__ Wih0, const float* __restrict__ Whh0,
    const float* __restrict__ bih0, const float* __restrict__ bhh0,
    const float* __restrict__ Wih1, const float* __restrict__ Whh1,
    const float* __restrict__ bih1, const float* __restrict__ bhh1,
    __bf16* h0_pub, __bf16* h1_pub,   // each: [4][B][H] bf16, 4-gen rotation
    unsigned* flags,                   // [4 groups][64] dword counters
    float* __restrict__ out) {
  __shared__ float sG[4][288];   // per-wave gate slab, stride 72 (2-way = free)

  const int wg   = blockIdx.x;
  const int g    = wg & 3;           // batch group; XCDs {g, g+4} under %8 rr
  const int wgl  = wg >> 2;          // 0..63 within group
  const int tid  = threadIdx.x;
  const int wv   = tid >> 6;
  const int lane = tid & 63;
  const int p    = lane >> 4;        // quad (= gate index for A/C rows)
  const int l15  = lane & 15;
  const int b    = g * 16 + l15;     // global batch
  const int ks   = p * 8;            // k offset inside a 32-chunk
  const int j    = wgl & 31;         // column-group within layer
  const int col4 = j * 16 + wv * 4;  // this wave's 4 h-columns
  const int row  = (l15 >> 2) * H_ + col4 + (l15 & 3);  // A-frag gate row for m=l15
  unsigned* gfl  = flags + (g << 6);

  if (wgl < 32) {
    // ---------------- layer 0 ----------------
    bf16x8 wh[16], wi[4];
    {
      const float* s = Whh0 + (size_t)row * H_ + ks;
#pragma unroll
      for (int kc = 0; kc < 16; ++kc) {
        bf16x8 a;
#pragma unroll
        for (int jj = 0; jj < 8; ++jj) a[jj] = (__bf16)s[kc * 32 + jj];
        wh[kc] = a;
      }
      const float* si = Wih0 + (size_t)row * F_ + ks;
#pragma unroll
      for (int kc = 0; kc < 4; ++kc) {
        bf16x8 a;
#pragma unroll
        for (int jj = 0; jj < 8; ++jj) a[jj] = (__bf16)si[kc * 32 + jj];
        wi[kc] = a;
      }
    }
    float bq[4];
#pragma unroll
    for (int r = 0; r < 4; ++r) {
      const int grow = p * H_ + col4 + r;
      bq[r] = bih0[grow] + bhh0[grow];
    }

    float c0 = 0.f;
    // x contribution for it=0 (no barrier precedes; xT ready at launch)
    f32x4 accb = {0.f, 0.f, 0.f, 0.f};
    {
      const __bf16* xrow = xT + ((size_t)0 * B_ + b) * F_;
#pragma unroll
      for (int kc = 0; kc < 4; ++kc) {
        bf16x8 xb = *(const bf16x8*)&xrow[kc * 32 + ks];
        accb = __builtin_amdgcn_mfma_f32_16x16x32_bf16(wi[kc], xb, accb, 0, 0, 0);
      }
    }

    for (int it = 0; it < T_; ++it) {
      const __bf16* h0r = h0_pub + ((it + 3) & 3) * (B_ * H_);
      unsigned* h0w = (unsigned*)(h0_pub + (it & 3) * (B_ * H_));

      f32x4 acc = {0.f, 0.f, 0.f, 0.f};
#pragma unroll
      for (int kc = 0; kc < 16; ++kc) {
        bf16x8 hb0 = *(const bf16x8*)&h0r[b * H_ + kc * 32 + ks];
        acc = __builtin_amdgcn_mfma_f32_16x16x32_bf16(wh[kc], hb0, acc, 0, 0, 0);
      }
#pragma unroll
      for (int r = 0; r < 4; ++r) {
        float v = acc[r] + accb[r] + bq[r];
        sG[wv][p * 72 + r * 16 + l15] = (p == 2) ? tanh_fast(v) : sigm(v);
      }
      // sG slab is per-wave private: lgkmcnt ordering suffices, no barrier
      float gi = sG[wv][0 * 72 + p * 16 + l15];
      float gf = sG[wv][1 * 72 + p * 16 + l15];
      float gg = sG[wv][2 * 72 + p * 16 + l15];
      float go = sG[wv][3 * 72 + p * 16 + l15];
      c0 = gf * c0 + gi * gg;
      float h = go * tanh_fast(c0);

      union { __bf16 bf; unsigned short u; } cv; cv.bf = (__bf16)h;
      unsigned o = (unsigned)__shfl_xor((int)(unsigned)cv.u, 16, 64);
      if ((p & 1) == 0) {
        unsigned v = (unsigned)cv.u | (o << 16);
        __hip_atomic_store(h0w + b * (H_ / 2) + (col4 >> 1) + (p >> 1), v,
                           __ATOMIC_RELAXED, __HIP_MEMORY_SCOPE_AGENT);
      }
      barrier_arrive(gfl, wgl, tid, (unsigned)(it + 1));
      if (it + 1 < T_) {
        // hide next step's x-GEMM under the flag-propagation latency
        const __bf16* xrow = xT + ((size_t)(it + 1) * B_ + b) * F_;
        f32x4 nb = {0.f, 0.f, 0.f, 0.f};
#pragma unroll
        for (int kc = 0; kc < 4; ++kc) {
          bf16x8 xb = *(const bf16x8*)&xrow[kc * 32 + ks];
          nb = __builtin_amdgcn_mfma_f32_16x16x32_bf16(wi[kc], xb, nb, 0, 0, 0);
        }
        accb = nb;
        barrier_wait(gfl, tid, (unsigned)(it + 1));
      }
      // final iteration: arrive only (layer-1 still needs our flag), then exit
    }
  } else {
    // ---------------- layer 1 ----------------
    bf16x8 wi[16], wh[16];
    {
      const float* s0 = Wih1 + (size_t)row * H_ + ks;
      const float* s1 = Whh1 + (size_t)row * H_ + ks;
#pragma unroll
      for (int kc = 0; kc < 16; ++kc) {
        bf16x8 a, c;
#pragma unroll
        for (int jj = 0; jj < 8; ++jj) {
          a[jj] = (__bf16)s0[kc * 32 + jj];
          c[jj] = (__bf16)s1[kc * 32 + jj];
        }
        wi[kc] = a; wh[kc] = c;
      }
    }
    float bq[4];
#pragma unroll
    for (int r = 0; r < 4; ++r) {
      const int grow = p * H_ + col4 + r;
      bq[r] = bih1[grow] + bhh1[grow];
    }

    float c1 = 0.f;
    barrier_arrive(gfl, wgl, tid, 1u);   // end of it=0 (layer-1 idle that step)
    barrier_wait(gfl, tid, 1u);
    for (int it = 1; it <= T_; ++it) {
      const __bf16* h0r = h0_pub + ((it + 3) & 3) * (B_ * H_);
      const __bf16* h1r = h1_pub + ((it + 3) & 3) * (B_ * H_);
      unsigned* h1w = (unsigned*)(h1_pub + (it & 3) * (B_ * H_));

      f32x4 acca = {0.f, 0.f, 0.f, 0.f};
      f32x4 accc = {0.f, 0.f, 0.f, 0.f};
#pragma unroll
      for (int kc = 0; kc < 16; ++kc) {
        bf16x8 hb0 = *(const bf16x8*)&h0r[b * H_ + kc * 32 + ks];
        bf16x8 hb1 = *(const bf16x8*)&h1r[b * H_ + kc * 32 + ks];
        acca = __builtin_amdgcn_mfma_f32_16x16x32_bf16(wi[kc], hb0, acca, 0, 0, 0);
        accc = __builtin_amdgcn_mfma_f32_16x16x32_bf16(wh[kc], hb1, accc, 0, 0, 0);
      }
#pragma unroll
      for (int r = 0; r < 4; ++r) {
        float v = acca[r] + accc[r] + bq[r];
        sG[wv][p * 72 + r * 16 + l15] = (p == 2) ? tanh_fast(v) : sigm(v);
      }
      float gi = sG[wv][0 * 72 + p * 16 + l15];
      float gf = sG[wv][1 * 72 + p * 16 + l15];
      float gg = sG[wv][2 * 72 + p * 16 + l15];
      float go = sG[wv][3 * 72 + p * 16 + l15];
      c1 = gf * c1 + gi * gg;
      float h = go * tanh_fast(c1);

      if (it < T_) {
        union { __bf16 bf; unsigned short u; } cv; cv.bf = (__bf16)h;
        unsigned o = (unsigned)__shfl_xor((int)(unsigned)cv.u, 16, 64);
        if ((p & 1) == 0) {
          unsigned v = (unsigned)cv.u | (o << 16);
          __hip_atomic_store(h1w + b * (H_ / 2) + (col4 >> 1) + (p >> 1), v,
                             __ATOMIC_RELAXED, __HIP_MEMORY_SCOPE_AGENT);
        }
        barrier_arrive(gfl, wgl, tid, (unsigned)(it + 1));
        barrier_wait(gfl, tid, (unsigned)(it + 1));
      } else {
        out[b * H_ + col4 + p] = h;   // final h1[T-1], fp32
      }
    }
  }
}

// Workspace layout:
//   [0]        flags: 4 groups x 64 x 4B = 1 KiB (16 KiB reserved)
//   [16384]    h0_pub: 4 gens x 64x512x2B = 262144 B
//   [278528]   h1_pub: 262144 B
//   [1 MiB]    xT: 16 MiB
// Zeroed region: [0, 540672).
extern "C" void kernel_launch(void* const* d_in, const int* in_sizes, int n_in,
                              void* d_out, int out_size, void* d_ws, size_t ws_size,
                              hipStream_t stream) {
  const float* x    = (const float*)d_in[0];
  const float* Wih0 = (const float*)d_in[1];
  const float* Whh0 = (const float*)d_in[2];
  const float* bih0 = (const float*)d_in[3];
  const float* bhh0 = (const float*)d_in[4];
  const float* Wih1 = (const float*)d_in[5];
  const float* Whh1 = (const float*)d_in[6];
  const float* bih1 = (const float*)d_in[7];
  const float* bhh1 = (const float*)d_in[8];
  float* out = (float*)d_out;

  char* ws = (char*)d_ws;
  unsigned* flags = (unsigned*)ws;
  __bf16* h0p = (__bf16*)(ws + 16384);
  __bf16* h1p = (__bf16*)(ws + 16384 + 4 * B_ * H_ * 2);
  __bf16* xT  = (__bf16*)(ws + (1 << 20));

  hipMemsetAsync(ws, 0, 16384 + 8 * B_ * H_ * 2, stream);

  transpose_x_kernel<<<dim3(B_ * 16), dim3(256), 0, stream>>>(x, xT);

  lstm_persistent<<<dim3(NWG), dim3(256), 0, stream>>>(
      xT, Wih0, Whh0, bih0, bhh0, Wih1, Whh1, bih1, bhh1,
      h0p, h1p, flags, out);
}

// Round 3
// 6314.650 us; speedup vs baseline: 1.2837x; 1.2837x over previous
//
#include <hip/hip_runtime.h>
#include <hip/hip_bf16.h>

// 2-layer LSTM, B=64, F=128, T=1024, H=512. Output = h_T of layer 1 (64x512 fp32).
// R6b: FENCE-FREE coherence (R6 with assembler syntax fix: offset: must precede
// sc0 sc1 on gfx950 global ops). R5 post-mortem: fan-in 256->64 and fetch /4 both
// neutral => per-step cost dominated by the per-step agent-acquire fence
// (buffer_inv: L2-wide invalidate, 32 CUs/XCD x 1024 steps). This round deletes
// the fence: h reads are issued as global_load_dwordx4 sc0 sc1 (bypass L1+L2,
// read the LLC coherence point directly -- same semantics as the proven flag
// poll). Release side unchanged (sc0sc1 write-through stores -> vmcnt drain at
// syncthreads -> flag store), so flag-at-LLC implies h-at-LLC; a coherence-point
// read issued after flag observation cannot be stale. L2 is never invalidated:
// xT/flags stay warm. Loads batched (16/32 per step) with ONE s_waitcnt vmcnt(0)
// + sched_barrier(0) before the MFMA chain (rule #18). launch_bounds(256,1) for
// VGPR headroom; occupancy is 1 WG/CU either way.
// Kept from R5: 4 batch-groups x 64 WGs, packed 4B flags (wave-0 coalesced poll),
// per-wave sG slab (no mid-step barrier), overlapped next-step x-GEMM.

#define B_ 64
#define F_ 128
#define T_ 1024
#define H_ 512
#define NWG 256

typedef __bf16 bf16x8 __attribute__((ext_vector_type(8)));
typedef float f32x4 __attribute__((ext_vector_type(4)));

__device__ __forceinline__ float sigm(float x) { return 1.0f / (1.0f + __expf(-x)); }
__device__ __forceinline__ float tanh_fast(float x) { return 1.0f - 2.0f / (__expf(2.0f * x) + 1.0f); }

// Coherence-point 16B load: bypass L1+L2, read LLC. No waitcnt here -- callers
// batch loads and drain once. NOTE: offset immediate BEFORE cache flags.
#define GLOAD_SC(dst, base, imm)                                      \
  asm volatile("global_load_dwordx4 %0, %1, off offset:%c2 sc0 sc1"   \
               : "=v"(dst) : "v"(base), "i"(imm))

// x (B,F,T) fp32 -> xT (T,B,F) bf16
__global__ __launch_bounds__(256) void transpose_x_kernel(const float* __restrict__ x,
                                                          __bf16* __restrict__ xT) {
  __shared__ float tile[F_][65];
  const int bb = blockIdx.x >> 4;
  const int tt = blockIdx.x & 15;
  const int tid = threadIdx.x;
  const int tl = tid & 63;
  const int f0 = tid >> 6;
  for (int fo = 0; fo < F_; fo += 4) {
    int f = fo + f0;
    tile[f][tl] = x[((size_t)bb * F_ + f) * T_ + tt * 64 + tl];
  }
  __syncthreads();
  const int fw = tid & 127;
  const int tg = tid >> 7;
  for (int to = 0; to < 64; to += 2) {
    int t = to + tg;
    xT[((size_t)(tt * 64 + t) * B_ + bb) * F_ + fw] = (__bf16)tile[fw][t];
  }
}

// arrive: drain publishes (syncthreads emits s_waitcnt vmcnt(0) before s_barrier,
// so all sc0sc1 stores are acked at the LLC) then post monotone counter.
__device__ __forceinline__ void barrier_arrive(unsigned* gfl, int wgl, int tid, unsigned tgt) {
  __syncthreads();
  if (tid == 0)
    __hip_atomic_store(&gfl[wgl], tgt, __ATOMIC_RELAXED, __HIP_MEMORY_SCOPE_AGENT);
}

// wait: wave 0 polls all 64 group flags (one coalesced load), then one barrier
// releases the other waves. NO acquire fence: all subsequent h reads go through
// sc0 sc1 (coherence-point) loads, so no stale cached line can be observed.
__device__ __forceinline__ void barrier_wait(unsigned* gfl, int tid, unsigned tgt) {
  if (tid < 64)
    while (__hip_atomic_load(&gfl[tid], __ATOMIC_RELAXED, __HIP_MEMORY_SCOPE_AGENT) < tgt)
      __builtin_amdgcn_s_sleep(1);
  __syncthreads();
}

__global__ __launch_bounds__(256, 1) void lstm_persistent(
    const __bf16* __restrict__ xT,
    const float* __restrict__ Wih0, const float* __restrict__ Whh0,
    const float* __restrict__ bih0, const float* __restrict__ bhh0,
    const float* __restrict__ Wih1, const float* __restrict__ Whh1,
    const float* __restrict__ bih1, const float* __restrict__ bhh1,
    __bf16* h0_pub, __bf16* h1_pub,   // each: [4][B][H] bf16, 4-gen rotation
    unsigned* flags,                   // [4 groups][64] dword counters
    float* __restrict__ out) {
  __shared__ float sG[4][288];   // per-wave gate slab, stride 72 (2-way = free)

  const int wg   = blockIdx.x;
  const int g    = wg & 3;           // batch group
  const int wgl  = wg >> 2;          // 0..63 within group
  const int tid  = threadIdx.x;
  const int wv   = tid >> 6;
  const int lane = tid & 63;
  const int p    = lane >> 4;        // quad (= gate index for A/C rows)
  const int l15  = lane & 15;
  const int b    = g * 16 + l15;     // global batch
  const int ks   = p * 8;            // k offset inside a 32-chunk
  const int j    = wgl & 31;         // column-group within layer
  const int col4 = j * 16 + wv * 4;  // this wave's 4 h-columns
  const int row  = (l15 >> 2) * H_ + col4 + (l15 & 3);  // A-frag gate row for m=l15
  unsigned* gfl  = flags + (g << 6);

  if (wgl < 32) {
    // ---------------- layer 0 ----------------
    bf16x8 wh[16], wi[4];
    {
      const float* s = Whh0 + (size_t)row * H_ + ks;
#pragma unroll
      for (int kc = 0; kc < 16; ++kc) {
        bf16x8 a;
#pragma unroll
        for (int jj = 0; jj < 8; ++jj) a[jj] = (__bf16)s[kc * 32 + jj];
        wh[kc] = a;
      }
      const float* si = Wih0 + (size_t)row * F_ + ks;
#pragma unroll
      for (int kc = 0; kc < 4; ++kc) {
        bf16x8 a;
#pragma unroll
        for (int jj = 0; jj < 8; ++jj) a[jj] = (__bf16)si[kc * 32 + jj];
        wi[kc] = a;
      }
    }
    float bq[4];
#pragma unroll
    for (int r = 0; r < 4; ++r) {
      const int grow = p * H_ + col4 + r;
      bq[r] = bih0[grow] + bhh0[grow];
    }

    float c0 = 0.f;
    // x contribution for it=0 (no barrier precedes; xT ready at launch)
    f32x4 accb = {0.f, 0.f, 0.f, 0.f};
    {
      const __bf16* xrow = xT + ((size_t)0 * B_ + b) * F_;
#pragma unroll
      for (int kc = 0; kc < 4; ++kc) {
        bf16x8 xb = *(const bf16x8*)&xrow[kc * 32 + ks];
        accb = __builtin_amdgcn_mfma_f32_16x16x32_bf16(wi[kc], xb, accb, 0, 0, 0);
      }
    }

    for (int it = 0; it < T_; ++it) {
      const __bf16* h0r = h0_pub + ((it + 3) & 3) * (B_ * H_);
      unsigned* h0w = (unsigned*)(h0_pub + (it & 3) * (B_ * H_));

      // batched coherence-point loads of this group's h0 slice, one drain
      const __bf16* hbase = h0r + b * H_ + ks;
      bf16x8 hb[16];
#pragma unroll
      for (int kc = 0; kc < 16; ++kc) GLOAD_SC(hb[kc], hbase, kc * 64);
      asm volatile("s_waitcnt vmcnt(0)" ::: "memory");
      __builtin_amdgcn_sched_barrier(0);

      f32x4 acc = {0.f, 0.f, 0.f, 0.f};
#pragma unroll
      for (int kc = 0; kc < 16; ++kc)
        acc = __builtin_amdgcn_mfma_f32_16x16x32_bf16(wh[kc], hb[kc], acc, 0, 0, 0);

#pragma unroll
      for (int r = 0; r < 4; ++r) {
        float v = acc[r] + accb[r] + bq[r];
        sG[wv][p * 72 + r * 16 + l15] = (p == 2) ? tanh_fast(v) : sigm(v);
      }
      // sG slab is per-wave private: lgkmcnt ordering suffices, no barrier
      float gi = sG[wv][0 * 72 + p * 16 + l15];
      float gf = sG[wv][1 * 72 + p * 16 + l15];
      float gg = sG[wv][2 * 72 + p * 16 + l15];
      float go = sG[wv][3 * 72 + p * 16 + l15];
      c0 = gf * c0 + gi * gg;
      float h = go * tanh_fast(c0);

      union { __bf16 bf; unsigned short u; } cv; cv.bf = (__bf16)h;
      unsigned o = (unsigned)__shfl_xor((int)(unsigned)cv.u, 16, 64);
      if ((p & 1) == 0) {
        unsigned v = (unsigned)cv.u | (o << 16);
        __hip_atomic_store(h0w + b * (H_ / 2) + (col4 >> 1) + (p >> 1), v,
                           __ATOMIC_RELAXED, __HIP_MEMORY_SCOPE_AGENT);
      }
      barrier_arrive(gfl, wgl, tid, (unsigned)(it + 1));
      if (it + 1 < T_) {
        // hide next step's x-GEMM under the flag-propagation latency
        const __bf16* xrow = xT + ((size_t)(it + 1) * B_ + b) * F_;
        f32x4 nb = {0.f, 0.f, 0.f, 0.f};
#pragma unroll
        for (int kc = 0; kc < 4; ++kc) {
          bf16x8 xb = *(const bf16x8*)&xrow[kc * 32 + ks];
          nb = __builtin_amdgcn_mfma_f32_16x16x32_bf16(wi[kc], xb, nb, 0, 0, 0);
        }
        accb = nb;
        barrier_wait(gfl, tid, (unsigned)(it + 1));
      }
      // final iteration: arrive only (layer-1 still needs our flag), then exit
    }
  } else {
    // ---------------- layer 1 ----------------
    bf16x8 wi[16], wh[16];
    {
      const float* s0 = Wih1 + (size_t)row * H_ + ks;
      const float* s1 = Whh1 + (size_t)row * H_ + ks;
#pragma unroll
      for (int kc = 0; kc < 16; ++kc) {
        bf16x8 a, c;
#pragma unroll
        for (int jj = 0; jj < 8; ++jj) {
          a[jj] = (__bf16)s0[kc * 32 + jj];
          c[jj] = (__bf16)s1[kc * 32 + jj];
        }
        wi[kc] = a; wh[kc] = c;
      }
    }
    float bq[4];
#pragma unroll
    for (int r = 0; r < 4; ++r) {
      const int grow = p * H_ + col4 + r;
      bq[r] = bih1[grow] + bhh1[grow];
    }

    float c1 = 0.f;
    barrier_arrive(gfl, wgl, tid, 1u);   // end of it=0 (layer-1 idle that step)
    barrier_wait(gfl, tid, 1u);
    for (int it = 1; it <= T_; ++it) {
      const __bf16* h0r = h0_pub + ((it + 3) & 3) * (B_ * H_);
      const __bf16* h1r = h1_pub + ((it + 3) & 3) * (B_ * H_);
      unsigned* h1w = (unsigned*)(h1_pub + (it & 3) * (B_ * H_));

      // batched coherence-point loads of h0+h1 slices, one drain
      const __bf16* ha_base = h0r + b * H_ + ks;
      const __bf16* hc_base = h1r + b * H_ + ks;
      bf16x8 ha[16], hc[16];
#pragma unroll
      for (int kc = 0; kc < 16; ++kc) {
        GLOAD_SC(ha[kc], ha_base, kc * 64);
        GLOAD_SC(hc[kc], hc_base, kc * 64);
      }
      asm volatile("s_waitcnt vmcnt(0)" ::: "memory");
      __builtin_amdgcn_sched_barrier(0);

      f32x4 acca = {0.f, 0.f, 0.f, 0.f};
      f32x4 accc = {0.f, 0.f, 0.f, 0.f};
#pragma unroll
      for (int kc = 0; kc < 16; ++kc) {
        acca = __builtin_amdgcn_mfma_f32_16x16x32_bf16(wi[kc], ha[kc], acca, 0, 0, 0);
        accc = __builtin_amdgcn_mfma_f32_16x16x32_bf16(wh[kc], hc[kc], accc, 0, 0, 0);
      }
#pragma unroll
      for (int r = 0; r < 4; ++r) {
        float v = acca[r] + accc[r] + bq[r];
        sG[wv][p * 72 + r * 16 + l15] = (p == 2) ? tanh_fast(v) : sigm(v);
      }
      float gi = sG[wv][0 * 72 + p * 16 + l15];
      float gf = sG[wv][1 * 72 + p * 16 + l15];
      float gg = sG[wv][2 * 72 + p * 16 + l15];
      float go = sG[wv][3 * 72 + p * 16 + l15];
      c1 = gf * c1 + gi * gg;
      float h = go * tanh_fast(c1);

      if (it < T_) {
        union { __bf16 bf; unsigned short u; } cv; cv.bf = (__bf16)h;
        unsigned o = (unsigned)__shfl_xor((int)(unsigned)cv.u, 16, 64);
        if ((p & 1) == 0) {
          unsigned v = (unsigned)cv.u | (o << 16);
          __hip_atomic_store(h1w + b * (H_ / 2) + (col4 >> 1) + (p >> 1), v,
                             __ATOMIC_RELAXED, __HIP_MEMORY_SCOPE_AGENT);
        }
        barrier_arrive(gfl, wgl, tid, (unsigned)(it + 1));
        barrier_wait(gfl, tid, (unsigned)(it + 1));
      } else {
        out[b * H_ + col4 + p] = h;   // final h1[T-1], fp32
      }
    }
  }
}

// Workspace layout:
//   [0]        flags: 4 groups x 64 x 4B = 1 KiB (16 KiB reserved)
//   [16384]    h0_pub: 4 gens x 64x512x2B = 262144 B
//   [278528]   h1_pub: 262144 B
//   [1 MiB]    xT: 16 MiB
// Zeroed region: [0, 540672).
extern "C" void kernel_launch(void* const* d_in, const int* in_sizes, int n_in,
                              void* d_out, int out_size, void* d_ws, size_t ws_size,
                              hipStream_t stream) {
  const float* x    = (const float*)d_in[0];
  const float* Wih0 = (const float*)d_in[1];
  const float* Whh0 = (const float*)d_in[2];
  const float* bih0 = (const float*)d_in[3];
  const float* bhh0 = (const float*)d_in[4];
  const float* Wih1 = (const float*)d_in[5];
  const float* Whh1 = (const float*)d_in[6];
  const float* bih1 = (const float*)d_in[7];
  const float* bhh1 = (const float*)d_in[8];
  float* out = (float*)d_out;

  char* ws = (char*)d_ws;
  unsigned* flags = (unsigned*)ws;
  __bf16* h0p = (__bf16*)(ws + 16384);
  __bf16* h1p = (__bf16*)(ws + 16384 + 4 * B_ * H_ * 2);
  __bf16* xT  = (__bf16*)(ws + (1 << 20));

  hipMemsetAsync(ws, 0, 16384 + 8 * B_ * H_ * 2, stream);

  transpose_x_kernel<<<dim3(B_ * 16), dim3(256), 0, stream>>>(x, xT);

  lstm_persistent<<<dim3(NWG), dim3(256), 0, stream>>>(
      xT, Wih0, Whh0, bih0, bhh0, Wih1, Whh1, bih1, bhh1,
      h0p, h1p, flags, out);
}

// Round 4
// 6270.414 us; speedup vs baseline: 1.2928x; 1.0071x over previous
//
#include <hip/hip_runtime.h>
#include <hip/hip_bf16.h>

// 2-layer LSTM, B=64, F=128, T=1024, H=512. Output = h_T of layer 1 (64x512 fp32).
// R7: coalesced h-publish + layer-decoupled flags.
// R6b post-mortem: fence removal gained 22% (8.1->6.3ms) but WRITE_SIZE=532MB
// (4x algorithmic 128MB) exposed the h-publish as 4B-per-lane partial-line
// write-through stores at 1KB stride: 128 scattered EA transactions per WG per
// step whose acks serialize into barrier_arrive's vmcnt(0) drain.
// This round:
//  (a) publish via LDS transpose: WG's 16 batches x 16 contiguous cols staged in
//      sH, wave0 stores 32x dwordx4 sc0sc1 (2 lanes/batch -> 32B bursts).
//      128 scattered 4B -> 32 coalesced 16B transactions; drain shortens.
//  (b) layer-split flags with slack: L0 step t waits {L0 peers >= t, L1 >= t-2}
//      (anti-overwrite of the 4-gen ring: L1 at step s reads gen (s-1)&3;
//      L1 done with step t-3 excludes collision s-1=t-4). L1 step s waits
//      {L0 >= s, L1 peers >= s}. L0 runs ahead; cross-layer jitter absorbed.
// Kept: fence-free sc0sc1 coherence-point h reads (R6b), 4 batch-groups x 64 WGs
// (R5), register-resident weights (R4), per-wave sG slab, x-GEMM prefetch.

#define B_ 64
#define F_ 128
#define T_ 1024
#define H_ 512
#define NWG 256

typedef __bf16 bf16x8 __attribute__((ext_vector_type(8)));
typedef float f32x4 __attribute__((ext_vector_type(4)));
typedef unsigned u32x4 __attribute__((ext_vector_type(4)));

__device__ __forceinline__ float sigm(float x) { return 1.0f / (1.0f + __expf(-x)); }
__device__ __forceinline__ float tanh_fast(float x) { return 1.0f - 2.0f / (__expf(2.0f * x) + 1.0f); }

// Coherence-point 16B load: bypass L1+L2, read LLC. Callers batch + drain once.
#define GLOAD_SC(dst, base, imm)                                      \
  asm volatile("global_load_dwordx4 %0, %1, off offset:%c2 sc0 sc1"   \
               : "=v"(dst) : "v"(base), "i"(imm))
// Coherence-point 16B store (write-through to LLC); ack drains at vmcnt(0).
#define GSTORE_SC(val, base)                                          \
  asm volatile("global_store_dwordx4 %0, %1, off sc0 sc1"             \
               :: "v"(base), "v"(val) : "memory")

// x (B,F,T) fp32 -> xT (T,B,F) bf16
__global__ __launch_bounds__(256) void transpose_x_kernel(const float* __restrict__ x,
                                                          __bf16* __restrict__ xT) {
  __shared__ float tile[F_][65];
  const int bb = blockIdx.x >> 4;
  const int tt = blockIdx.x & 15;
  const int tid = threadIdx.x;
  const int tl = tid & 63;
  const int f0 = tid >> 6;
  for (int fo = 0; fo < F_; fo += 4) {
    int f = fo + f0;
    tile[f][tl] = x[((size_t)bb * F_ + f) * T_ + tt * 64 + tl];
  }
  __syncthreads();
  const int fw = tid & 127;
  const int tg = tid >> 7;
  for (int to = 0; to < 64; to += 2) {
    int t = to + tg;
    xT[((size_t)(tt * 64 + t) * B_ + bb) * F_ + fw] = (__bf16)tile[fw][t];
  }
}

// arrive: __syncthreads drains each wave's vmcnt (publish stores acked at LLC)
// before tid0 posts the monotone counter.
__device__ __forceinline__ void arrive_flag(unsigned* gfl, int wgl, int tid, unsigned tgt) {
  __syncthreads();
  if (tid == 0)
    __hip_atomic_store(&gfl[wgl], tgt, __ATOMIC_RELAXED, __HIP_MEMORY_SCOPE_AGENT);
}

// wait: wave 0 polls 64 group flags with per-half targets (flags[0..32)=L0 WGs,
// flags[32..64)=L1 WGs). No acquire fence: all h reads are sc0sc1.
__device__ __forceinline__ void wait_split(unsigned* gfl, int tid, unsigned tgtL0, unsigned tgtL1) {
  if (tid < 64) {
    const unsigned tgt = (tid < 32) ? tgtL0 : tgtL1;
    while (__hip_atomic_load(&gfl[tid], __ATOMIC_RELAXED, __HIP_MEMORY_SCOPE_AGENT) < tgt)
      __builtin_amdgcn_s_sleep(1);
  }
  __syncthreads();
}

__global__ __launch_bounds__(256, 1) void lstm_persistent(
    const __bf16* __restrict__ xT,
    const float* __restrict__ Wih0, const float* __restrict__ Whh0,
    const float* __restrict__ bih0, const float* __restrict__ bhh0,
    const float* __restrict__ Wih1, const float* __restrict__ Whh1,
    const float* __restrict__ bih1, const float* __restrict__ bhh1,
    __bf16* h0_pub, __bf16* h1_pub,   // each: [4][B][H] bf16, 4-gen rotation
    unsigned* flags,                   // [4 groups][64] dword counters
    float* __restrict__ out) {
  __shared__ float sG[4][288];             // per-wave gate slab, stride 72
  __shared__ __align__(16) __bf16 sH[16][24];  // publish transpose: 16 batches x 16 cols (stride 24)

  const int wg   = blockIdx.x;
  const int g    = wg & 3;           // batch group
  const int wgl  = wg >> 2;          // 0..63 within group
  const int tid  = threadIdx.x;
  const int wv   = tid >> 6;
  const int lane = tid & 63;
  const int p    = lane >> 4;        // quad (= gate index for A/C rows)
  const int l15  = lane & 15;
  const int b    = g * 16 + l15;     // global batch
  const int ks   = p * 8;            // k offset inside a 32-chunk
  const int j    = wgl & 31;         // column-group within layer
  const int col4 = j * 16 + wv * 4;  // this wave's 4 h-columns
  const int row  = (l15 >> 2) * H_ + col4 + (l15 & 3);  // A-frag gate row for m=l15
  unsigned* gfl  = flags + (g << 6);
  // publish-store lane mapping (tid<32): 2 lanes per batch, 16B each
  const int pb   = tid >> 1;         // batch within group
  const int phf  = tid & 1;          // which 16B half of the 32B chunk

  if (wgl < 32) {
    // ---------------- layer 0 ----------------
    bf16x8 wh[16], wi[4];
    {
      const float* s = Whh0 + (size_t)row * H_ + ks;
#pragma unroll
      for (int kc = 0; kc < 16; ++kc) {
        bf16x8 a;
#pragma unroll
        for (int jj = 0; jj < 8; ++jj) a[jj] = (__bf16)s[kc * 32 + jj];
        wh[kc] = a;
      }
      const float* si = Wih0 + (size_t)row * F_ + ks;
#pragma unroll
      for (int kc = 0; kc < 4; ++kc) {
        bf16x8 a;
#pragma unroll
        for (int jj = 0; jj < 8; ++jj) a[jj] = (__bf16)si[kc * 32 + jj];
        wi[kc] = a;
      }
    }
    float bq[4];
#pragma unroll
    for (int r = 0; r < 4; ++r) {
      const int grow = p * H_ + col4 + r;
      bq[r] = bih0[grow] + bhh0[grow];
    }

    float c0 = 0.f;
    // x contribution for it=0 (no barrier precedes; xT ready at launch)
    f32x4 accb = {0.f, 0.f, 0.f, 0.f};
    {
      const __bf16* xrow = xT + ((size_t)0 * B_ + b) * F_;
#pragma unroll
      for (int kc = 0; kc < 4; ++kc) {
        bf16x8 xb = *(const bf16x8*)&xrow[kc * 32 + ks];
        accb = __builtin_amdgcn_mfma_f32_16x16x32_bf16(wi[kc], xb, accb, 0, 0, 0);
      }
    }

    for (int it = 0; it < T_; ++it) {
      const __bf16* h0r = h0_pub + ((it + 3) & 3) * (B_ * H_);
      __bf16* h0w = h0_pub + (it & 3) * (B_ * H_);

      // batched coherence-point loads of this group's h0 slice, one drain
      const __bf16* hbase = h0r + b * H_ + ks;
      bf16x8 hb[16];
#pragma unroll
      for (int kc = 0; kc < 16; ++kc) GLOAD_SC(hb[kc], hbase, kc * 64);
      asm volatile("s_waitcnt vmcnt(0)" ::: "memory");
      __builtin_amdgcn_sched_barrier(0);

      f32x4 acc = {0.f, 0.f, 0.f, 0.f};
#pragma unroll
      for (int kc = 0; kc < 16; ++kc)
        acc = __builtin_amdgcn_mfma_f32_16x16x32_bf16(wh[kc], hb[kc], acc, 0, 0, 0);

#pragma unroll
      for (int r = 0; r < 4; ++r) {
        float v = acc[r] + accb[r] + bq[r];
        sG[wv][p * 72 + r * 16 + l15] = (p == 2) ? tanh_fast(v) : sigm(v);
      }
      // sG slab is per-wave private: lgkmcnt ordering suffices, no barrier
      float gi = sG[wv][0 * 72 + p * 16 + l15];
      float gf = sG[wv][1 * 72 + p * 16 + l15];
      float gg = sG[wv][2 * 72 + p * 16 + l15];
      float go = sG[wv][3 * 72 + p * 16 + l15];
      c0 = gf * c0 + gi * gg;
      float h = go * tanh_fast(c0);

      // coalesced publish: stage WG tile (16 batches x 16 cols) then wave0 stores
      sH[l15][wv * 4 + p] = (__bf16)h;
      __syncthreads();
      if (tid < 32) {
        u32x4 d = *(const u32x4*)&sH[pb][phf * 8];
        __bf16* dst = h0w + (size_t)(g * 16 + pb) * H_ + j * 16 + phf * 8;
        GSTORE_SC(d, dst);
      }
      if (it + 1 < T_) {
        // next step's x-GEMM issued now: hides publish-store flight
        const __bf16* xrow = xT + ((size_t)(it + 1) * B_ + b) * F_;
        f32x4 nb = {0.f, 0.f, 0.f, 0.f};
#pragma unroll
        for (int kc = 0; kc < 4; ++kc) {
          bf16x8 xb = *(const bf16x8*)&xrow[kc * 32 + ks];
          nb = __builtin_amdgcn_mfma_f32_16x16x32_bf16(wi[kc], xb, nb, 0, 0, 0);
        }
        accb = nb;
      }
      arrive_flag(gfl, wgl, tid, (unsigned)(it + 1));
      if (it + 1 < T_) {
        // entering step t=it+1: L0 peers >= t; L1 >= t-2 (4-gen anti-overwrite)
        const unsigned tgtL1 = (it >= 1) ? (unsigned)(it - 1) : 0u;
        wait_split(gfl, tid, (unsigned)(it + 1), tgtL1);
      }
    }
  } else {
    // ---------------- layer 1 ----------------
    bf16x8 wi[16], wh[16];
    {
      const float* s0 = Wih1 + (size_t)row * H_ + ks;
      const float* s1 = Whh1 + (size_t)row * H_ + ks;
#pragma unroll
      for (int kc = 0; kc < 16; ++kc) {
        bf16x8 a, c;
#pragma unroll
        for (int jj = 0; jj < 8; ++jj) {
          a[jj] = (__bf16)s0[kc * 32 + jj];
          c[jj] = (__bf16)s1[kc * 32 + jj];
        }
        wi[kc] = a; wh[kc] = c;
      }
    }
    float bq[4];
#pragma unroll
    for (int r = 0; r < 4; ++r) {
      const int grow = p * H_ + col4 + r;
      bq[r] = bih1[grow] + bhh1[grow];
    }

    float c1 = 0.f;
    arrive_flag(gfl, wgl, tid, 1u);   // "step 0 done" (layer-1 idle that step)
    wait_split(gfl, tid, 1u, 1u);
    for (int it = 1; it <= T_; ++it) {
      const __bf16* h0r = h0_pub + ((it + 3) & 3) * (B_ * H_);
      const __bf16* h1r = h1_pub + ((it + 3) & 3) * (B_ * H_);
      __bf16* h1w = h1_pub + (it & 3) * (B_ * H_);

      // batched coherence-point loads of h0+h1 slices, one drain
      const __bf16* ha_base = h0r + b * H_ + ks;
      const __bf16* hc_base = h1r + b * H_ + ks;
      bf16x8 ha[16], hc[16];
#pragma unroll
      for (int kc = 0; kc < 16; ++kc) {
        GLOAD_SC(ha[kc], ha_base, kc * 64);
        GLOAD_SC(hc[kc], hc_base, kc * 64);
      }
      asm volatile("s_waitcnt vmcnt(0)" ::: "memory");
      __builtin_amdgcn_sched_barrier(0);

      f32x4 acca = {0.f, 0.f, 0.f, 0.f};
      f32x4 accc = {0.f, 0.f, 0.f, 0.f};
#pragma unroll
      for (int kc = 0; kc < 16; ++kc) {
        acca = __builtin_amdgcn_mfma_f32_16x16x32_bf16(wi[kc], ha[kc], acca, 0, 0, 0);
        accc = __builtin_amdgcn_mfma_f32_16x16x32_bf16(wh[kc], hc[kc], accc, 0, 0, 0);
      }
#pragma unroll
      for (int r = 0; r < 4; ++r) {
        float v = acca[r] + accc[r] + bq[r];
        sG[wv][p * 72 + r * 16 + l15] = (p == 2) ? tanh_fast(v) : sigm(v);
      }
      float gi = sG[wv][0 * 72 + p * 16 + l15];
      float gf = sG[wv][1 * 72 + p * 16 + l15];
      float gg = sG[wv][2 * 72 + p * 16 + l15];
      float go = sG[wv][3 * 72 + p * 16 + l15];
      c1 = gf * c1 + gi * gg;
      float h = go * tanh_fast(c1);

      if (it < T_) {
        // coalesced publish of h1 tile
        sH[l15][wv * 4 + p] = (__bf16)h;
        __syncthreads();
        if (tid < 32) {
          u32x4 d = *(const u32x4*)&sH[pb][phf * 8];
          __bf16* dst = h1w + (size_t)(g * 16 + pb) * H_ + j * 16 + phf * 8;
          GSTORE_SC(d, dst);
        }
        arrive_flag(gfl, wgl, tid, (unsigned)(it + 1));
        // entering step it+1: need h0(it) => L0 >= it+1; h1 peers >= it+1
        wait_split(gfl, tid, (unsigned)(it + 1), (unsigned)(it + 1));
      } else {
        out[b * H_ + col4 + p] = h;   // final h1[T-1], fp32
      }
    }
  }
}

// Workspace layout:
//   [0]        flags: 4 groups x 64 x 4B = 1 KiB (16 KiB reserved)
//   [16384]    h0_pub: 4 gens x 64x512x2B = 262144 B
//   [278528]   h1_pub: 262144 B
//   [1 MiB]    xT: 16 MiB
// Zeroed region: [0, 540672).
extern "C" void kernel_launch(void* const* d_in, const int* in_sizes, int n_in,
                              void* d_out, int out_size, void* d_ws, size_t ws_size,
                              hipStream_t stream) {
  const float* x    = (const float*)d_in[0];
  const float* Wih0 = (const float*)d_in[1];
  const float* Whh0 = (const float*)d_in[2];
  const float* bih0 = (const float*)d_in[3];
  const float* bhh0 = (const float*)d_in[4];
  const float* Wih1 = (const float*)d_in[5];
  const float* Whh1 = (const float*)d_in[6];
  const float* bih1 = (const float*)d_in[7];
  const float* bhh1 = (const float*)d_in[8];
  float* out = (float*)d_out;

  char* ws = (char*)d_ws;
  unsigned* flags = (unsigned*)ws;
  __bf16* h0p = (__bf16*)(ws + 16384);
  __bf16* h1p = (__bf16*)(ws + 16384 + 4 * B_ * H_ * 2);
  __bf16* xT  = (__bf16*)(ws + (1 << 20));

  hipMemsetAsync(ws, 0, 16384 + 8 * B_ * H_ * 2, stream);

  transpose_x_kernel<<<dim3(B_ * 16), dim3(256), 0, stream>>>(x, xT);

  lstm_persistent<<<dim3(NWG), dim3(256), 0, stream>>>(
      xT, Wih0, Whh0, bih0, bhh0, Wih1, Whh1, bih1, bhh1,
      h0p, h1p, flags, out);
}

// Round 6
// 3835.839 us; speedup vs baseline: 2.1133x; 1.6347x over previous
//
#include <hip/hip_runtime.h>
#include <hip/hip_bf16.h>

// 2-layer LSTM, B=64, F=128, T=1024, H=512. Output = h_T of layer 1 (64x512 fp32).
// R8b: LDS-deduplicated h staging (R8 resubmit after infra failure; s_sleep(1)
// restored in the poll for watchdog safety).
// R7 post-mortem: coalesced publish dropped WRITE_SIZE 532->139MB but dur was
// neutral -- and the x-prefetch placed before arrive_flag put a cold-HBM load
// into every flag post's vmcnt(0) drain (regression masking the gain).
// Root cause found in the address math: all 4 waves of each WG load the SAME
// h slice (b,ks independent of wv). With sc0sc1 (L2-bypass) reads there is NO
// cache dedup: 4x duplicate LLC reads = ~24MB/step grid-wide in a thundering
// herd after each flag release -> LLC congestion inflates every latency.
// This round:
//  (a) stage h through LDS: wave wv loads k-chunks [4wv,4wv+4) (4KB), one
//      vmcnt drain, ds_write to sA[kc][batch][32] (conflict-free: the 64
//      lanes of a wave write 64 distinct 16B chunks covering a contiguous
//      1KB row), syncthreads, all waves ds_read_b128 fragments.
//      LLC h traffic /4 (24->6 MB/step).
//  (b) x-prefetch AFTER arrive_flag (R6b placement): flag post drains only
//      the 32 coalesced publish stores.
// Kept: fence-free sc0sc1 coherence (R6b), coalesced publish + layer-split
// slack flags (R7), 4 batch-groups (R5), register-resident weights (R4).

#define B_ 64
#define F_ 128
#define T_ 1024
#define H_ 512
#define NWG 256

typedef __bf16 bf16x8 __attribute__((ext_vector_type(8)));
typedef float f32x4 __attribute__((ext_vector_type(4)));
typedef unsigned u32x4 __attribute__((ext_vector_type(4)));

__device__ __forceinline__ float sigm(float x) { return 1.0f / (1.0f + __expf(-x)); }
__device__ __forceinline__ float tanh_fast(float x) { return 1.0f - 2.0f / (__expf(2.0f * x) + 1.0f); }

// Coherence-point 16B load: bypass L1+L2, read LLC. Callers batch + drain once.
#define GLOAD_SC(dst, base, imm)                                      \
  asm volatile("global_load_dwordx4 %0, %1, off offset:%c2 sc0 sc1"   \
               : "=v"(dst) : "v"(base), "i"(imm))
// Coherence-point 16B store (write-through to LLC); ack drains at vmcnt(0).
#define GSTORE_SC(val, base)                                          \
  asm volatile("global_store_dwordx4 %0, %1, off sc0 sc1"             \
               :: "v"(base), "v"(val) : "memory")

// x (B,F,T) fp32 -> xT (T,B,F) bf16
__global__ __launch_bounds__(256) void transpose_x_kernel(const float* __restrict__ x,
                                                          __bf16* __restrict__ xT) {
  __shared__ float tile[F_][65];
  const int bb = blockIdx.x >> 4;
  const int tt = blockIdx.x & 15;
  const int tid = threadIdx.x;
  const int tl = tid & 63;
  const int f0 = tid >> 6;
  for (int fo = 0; fo < F_; fo += 4) {
    int f = fo + f0;
    tile[f][tl] = x[((size_t)bb * F_ + f) * T_ + tt * 64 + tl];
  }
  __syncthreads();
  const int fw = tid & 127;
  const int tg = tid >> 7;
  for (int to = 0; to < 64; to += 2) {
    int t = to + tg;
    xT[((size_t)(tt * 64 + t) * B_ + bb) * F_ + fw] = (__bf16)tile[fw][t];
  }
}

// arrive: __syncthreads drains each wave's vmcnt (publish stores acked at LLC)
// before tid0 posts the monotone counter.
__device__ __forceinline__ void arrive_flag(unsigned* gfl, int wgl, int tid, unsigned tgt) {
  __syncthreads();
  if (tid == 0)
    __hip_atomic_store(&gfl[wgl], tgt, __ATOMIC_RELAXED, __HIP_MEMORY_SCOPE_AGENT);
}

// wait: wave 0 polls 64 group flags with per-half targets
// (flags[0..32)=L0 WGs, [32..64)=L1 WGs). No acquire fence: h reads are sc0sc1.
__device__ __forceinline__ void wait_split(unsigned* gfl, int tid, unsigned tgtL0, unsigned tgtL1) {
  if (tid < 64) {
    const unsigned tgt = (tid < 32) ? tgtL0 : tgtL1;
    while (__hip_atomic_load(&gfl[tid], __ATOMIC_RELAXED, __HIP_MEMORY_SCOPE_AGENT) < tgt)
      __builtin_amdgcn_s_sleep(1);
  }
  __syncthreads();
}

__global__ __launch_bounds__(256, 1) void lstm_persistent(
    const __bf16* __restrict__ xT,
    const float* __restrict__ Wih0, const float* __restrict__ Whh0,
    const float* __restrict__ bih0, const float* __restrict__ bhh0,
    const float* __restrict__ Wih1, const float* __restrict__ Whh1,
    const float* __restrict__ bih1, const float* __restrict__ bhh1,
    __bf16* h0_pub, __bf16* h1_pub,   // each: [4][B][H] bf16, 4-gen rotation
    unsigned* flags,                   // [4 groups][64] dword counters
    float* __restrict__ out) {
  __shared__ float sG[4][288];                  // per-wave gate slab, stride 72
  __shared__ __align__(16) __bf16 sH[16][24];   // publish transpose tile
  __shared__ __align__(16) __bf16 sA0[16][16][32];  // h0 staging [kc][b][col] 16KB
  __shared__ __align__(16) __bf16 sA1[16][16][32];  // h1 staging (layer-1) 16KB

  const int wg   = blockIdx.x;
  const int g    = wg & 3;           // batch group
  const int wgl  = wg >> 2;          // 0..63 within group
  const int tid  = threadIdx.x;
  const int wv   = tid >> 6;
  const int lane = tid & 63;
  const int p    = lane >> 4;        // quad (= gate index for A/C rows)
  const int l15  = lane & 15;
  const int b    = g * 16 + l15;     // global batch
  const int ks   = p * 8;            // k offset inside a 32-chunk
  const int j    = wgl & 31;         // column-group within layer
  const int col4 = j * 16 + wv * 4;  // this wave's 4 h-columns
  const int row  = (l15 >> 2) * H_ + col4 + (l15 & 3);  // A-frag gate row for m=l15
  unsigned* gfl  = flags + (g << 6);
  // publish-store lane mapping (tid<32): 2 lanes per batch, 16B each
  const int pb   = tid >> 1;         // batch within group
  const int phf  = tid & 1;          // which 16B half of the 32B chunk

  if (wgl < 32) {
    // ---------------- layer 0 ----------------
    bf16x8 wh[16], wi[4];
    {
      const float* s = Whh0 + (size_t)row * H_ + ks;
#pragma unroll
      for (int kc = 0; kc < 16; ++kc) {
        bf16x8 a;
#pragma unroll
        for (int jj = 0; jj < 8; ++jj) a[jj] = (__bf16)s[kc * 32 + jj];
        wh[kc] = a;
      }
      const float* si = Wih0 + (size_t)row * F_ + ks;
#pragma unroll
      for (int kc = 0; kc < 4; ++kc) {
        bf16x8 a;
#pragma unroll
        for (int jj = 0; jj < 8; ++jj) a[jj] = (__bf16)si[kc * 32 + jj];
        wi[kc] = a;
      }
    }
    float bq[4];
#pragma unroll
    for (int r = 0; r < 4; ++r) {
      const int grow = p * H_ + col4 + r;
      bq[r] = bih0[grow] + bhh0[grow];
    }

    float c0 = 0.f;
    // x contribution for it=0 (no barrier precedes; xT ready at launch)
    f32x4 accb = {0.f, 0.f, 0.f, 0.f};
    {
      const __bf16* xrow = xT + ((size_t)0 * B_ + b) * F_;
#pragma unroll
      for (int kc = 0; kc < 4; ++kc) {
        bf16x8 xb = *(const bf16x8*)&xrow[kc * 32 + ks];
        accb = __builtin_amdgcn_mfma_f32_16x16x32_bf16(wi[kc], xb, accb, 0, 0, 0);
      }
    }

    for (int it = 0; it < T_; ++it) {
      const __bf16* h0r = h0_pub + ((it + 3) & 3) * (B_ * H_);
      __bf16* h0w = h0_pub + (it & 3) * (B_ * H_);

      // ---- stage h0 slice through LDS (each wave loads k-chunks [4wv,4wv+4)) ----
      {
        const __bf16* src = h0r + (size_t)b * H_ + wv * 128 + ks;
        bf16x8 st0, st1, st2, st3;
        GLOAD_SC(st0, src, 0);
        GLOAD_SC(st1, src, 64);
        GLOAD_SC(st2, src, 128);
        GLOAD_SC(st3, src, 192);
        asm volatile("s_waitcnt vmcnt(0)" ::: "memory");
        __builtin_amdgcn_sched_barrier(0);
        *(bf16x8*)&sA0[wv * 4 + 0][l15][ks] = st0;
        *(bf16x8*)&sA0[wv * 4 + 1][l15][ks] = st1;
        *(bf16x8*)&sA0[wv * 4 + 2][l15][ks] = st2;
        *(bf16x8*)&sA0[wv * 4 + 3][l15][ks] = st3;
      }
      __syncthreads();

      f32x4 acc = {0.f, 0.f, 0.f, 0.f};
#pragma unroll
      for (int kc = 0; kc < 16; ++kc) {
        bf16x8 hb = *(const bf16x8*)&sA0[kc][l15][ks];
        acc = __builtin_amdgcn_mfma_f32_16x16x32_bf16(wh[kc], hb, acc, 0, 0, 0);
      }

#pragma unroll
      for (int r = 0; r < 4; ++r) {
        float v = acc[r] + accb[r] + bq[r];
        sG[wv][p * 72 + r * 16 + l15] = (p == 2) ? tanh_fast(v) : sigm(v);
      }
      // sG slab is per-wave private: lgkmcnt ordering suffices, no barrier
      float gi = sG[wv][0 * 72 + p * 16 + l15];
      float gf = sG[wv][1 * 72 + p * 16 + l15];
      float gg = sG[wv][2 * 72 + p * 16 + l15];
      float go = sG[wv][3 * 72 + p * 16 + l15];
      c0 = gf * c0 + gi * gg;
      float h = go * tanh_fast(c0);

      // coalesced publish: stage WG tile (16 batches x 16 cols) then wave0 stores
      sH[l15][wv * 4 + p] = (__bf16)h;
      __syncthreads();
      if (tid < 32) {
        u32x4 d = *(const u32x4*)&sH[pb][phf * 8];
        __bf16* dst = h0w + (size_t)(g * 16 + pb) * H_ + j * 16 + phf * 8;
        GSTORE_SC(d, dst);
      }
      arrive_flag(gfl, wgl, tid, (unsigned)(it + 1));
      if (it + 1 < T_) {
        // next step's x-GEMM: loads+MFMA hidden under the peer wait
        const __bf16* xrow = xT + ((size_t)(it + 1) * B_ + b) * F_;
        f32x4 nb = {0.f, 0.f, 0.f, 0.f};
#pragma unroll
        for (int kc = 0; kc < 4; ++kc) {
          bf16x8 xb = *(const bf16x8*)&xrow[kc * 32 + ks];
          nb = __builtin_amdgcn_mfma_f32_16x16x32_bf16(wi[kc], xb, nb, 0, 0, 0);
        }
        accb = nb;
        // entering step t=it+1: L0 peers >= t; L1 >= t-2 (4-gen anti-overwrite)
        const unsigned tgtL1 = (it >= 1) ? (unsigned)(it - 1) : 0u;
        wait_split(gfl, tid, (unsigned)(it + 1), tgtL1);
      }
    }
  } else {
    // ---------------- layer 1 ----------------
    bf16x8 wi[16], wh[16];
    {
      const float* s0 = Wih1 + (size_t)row * H_ + ks;
      const float* s1 = Whh1 + (size_t)row * H_ + ks;
#pragma unroll
      for (int kc = 0; kc < 16; ++kc) {
        bf16x8 a, c;
#pragma unroll
        for (int jj = 0; jj < 8; ++jj) {
          a[jj] = (__bf16)s0[kc * 32 + jj];
          c[jj] = (__bf16)s1[kc * 32 + jj];
        }
        wi[kc] = a; wh[kc] = c;
      }
    }
    float bq[4];
#pragma unroll
    for (int r = 0; r < 4; ++r) {
      const int grow = p * H_ + col4 + r;
      bq[r] = bih1[grow] + bhh1[grow];
    }

    float c1 = 0.f;
    arrive_flag(gfl, wgl, tid, 1u);   // "step 0 done" (layer-1 idle that step)
    wait_split(gfl, tid, 1u, 1u);
    for (int it = 1; it <= T_; ++it) {
      const __bf16* h0r = h0_pub + ((it + 3) & 3) * (B_ * H_);
      const __bf16* h1r = h1_pub + ((it + 3) & 3) * (B_ * H_);
      __bf16* h1w = h1_pub + (it & 3) * (B_ * H_);

      // ---- stage h0+h1 slices through LDS ----
      {
        const __bf16* sa = h0r + (size_t)b * H_ + wv * 128 + ks;
        const __bf16* sc = h1r + (size_t)b * H_ + wv * 128 + ks;
        bf16x8 sa0, sa1, sa2, sa3, sc0, sc1_, sc2, sc3;
        GLOAD_SC(sa0, sa, 0);
        GLOAD_SC(sa1, sa, 64);
        GLOAD_SC(sa2, sa, 128);
        GLOAD_SC(sa3, sa, 192);
        GLOAD_SC(sc0, sc, 0);
        GLOAD_SC(sc1_, sc, 64);
        GLOAD_SC(sc2, sc, 128);
        GLOAD_SC(sc3, sc, 192);
        asm volatile("s_waitcnt vmcnt(0)" ::: "memory");
        __builtin_amdgcn_sched_barrier(0);
        *(bf16x8*)&sA0[wv * 4 + 0][l15][ks] = sa0;
        *(bf16x8*)&sA0[wv * 4 + 1][l15][ks] = sa1;
        *(bf16x8*)&sA0[wv * 4 + 2][l15][ks] = sa2;
        *(bf16x8*)&sA0[wv * 4 + 3][l15][ks] = sa3;
        *(bf16x8*)&sA1[wv * 4 + 0][l15][ks] = sc0;
        *(bf16x8*)&sA1[wv * 4 + 1][l15][ks] = sc1_;
        *(bf16x8*)&sA1[wv * 4 + 2][l15][ks] = sc2;
        *(bf16x8*)&sA1[wv * 4 + 3][l15][ks] = sc3;
      }
      __syncthreads();

      f32x4 acca = {0.f, 0.f, 0.f, 0.f};
      f32x4 accc = {0.f, 0.f, 0.f, 0.f};
#pragma unroll
      for (int kc = 0; kc < 16; ++kc) {
        bf16x8 ha = *(const bf16x8*)&sA0[kc][l15][ks];
        bf16x8 hc = *(const bf16x8*)&sA1[kc][l15][ks];
        acca = __builtin_amdgcn_mfma_f32_16x16x32_bf16(wi[kc], ha, acca, 0, 0, 0);
        accc = __builtin_amdgcn_mfma_f32_16x16x32_bf16(wh[kc], hc, accc, 0, 0, 0);
      }
#pragma unroll
      for (int r = 0; r < 4; ++r) {
        float v = acca[r] + accc[r] + bq[r];
        sG[wv][p * 72 + r * 16 + l15] = (p == 2) ? tanh_fast(v) : sigm(v);
      }
      float gi = sG[wv][0 * 72 + p * 16 + l15];
      float gf = sG[wv][1 * 72 + p * 16 + l15];
      float gg = sG[wv][2 * 72 + p * 16 + l15];
      float go = sG[wv][3 * 72 + p * 16 + l15];
      c1 = gf * c1 + gi * gg;
      float h = go * tanh_fast(c1);

      if (it < T_) {
        // coalesced publish of h1 tile
        sH[l15][wv * 4 + p] = (__bf16)h;
        __syncthreads();
        if (tid < 32) {
          u32x4 d = *(const u32x4*)&sH[pb][phf * 8];
          __bf16* dst = h1w + (size_t)(g * 16 + pb) * H_ + j * 16 + phf * 8;
          GSTORE_SC(d, dst);
        }
        arrive_flag(gfl, wgl, tid, (unsigned)(it + 1));
        // entering step it+1: need h0(it) => L0 >= it+1; h1 peers >= it+1
        wait_split(gfl, tid, (unsigned)(it + 1), (unsigned)(it + 1));
      } else {
        out[b * H_ + col4 + p] = h;   // final h1[T-1], fp32
      }
    }
  }
}

// Workspace layout:
//   [0]        flags: 4 groups x 64 x 4B = 1 KiB (16 KiB reserved)
//   [16384]    h0_pub: 4 gens x 64x512x2B = 262144 B
//   [278528]   h1_pub: 262144 B
//   [1 MiB]    xT: 16 MiB
// Zeroed region: [0, 540672).
extern "C" void kernel_launch(void* const* d_in, const int* in_sizes, int n_in,
                              void* d_out, int out_size, void* d_ws, size_t ws_size,
                              hipStream_t stream) {
  const float* x    = (const float*)d_in[0];
  const float* Wih0 = (const float*)d_in[1];
  const float* Whh0 = (const float*)d_in[2];
  const float* bih0 = (const float*)d_in[3];
  const float* bhh0 = (const float*)d_in[4];
  const float* Wih1 = (const float*)d_in[5];
  const float* Whh1 = (const float*)d_in[6];
  const float* bih1 = (const float*)d_in[7];
  const float* bhh1 = (const float*)d_in[8];
  float* out = (float*)d_out;

  char* ws = (char*)d_ws;
  unsigned* flags = (unsigned*)ws;
  __bf16* h0p = (__bf16*)(ws + 16384);
  __bf16* h1p = (__bf16*)(ws + 16384 + 4 * B_ * H_ * 2);
  __bf16* xT  = (__bf16*)(ws + (1 << 20));

  hipMemsetAsync(ws, 0, 16384 + 8 * B_ * H_ * 2, stream);

  transpose_x_kernel<<<dim3(B_ * 16), dim3(256), 0, stream>>>(x, xT);

  lstm_persistent<<<dim3(NWG), dim3(256), 0, stream>>>(
      xT, Wih0, Whh0, bih0, bhh0, Wih1, Whh1, bih1, bhh1,
      h0p, h1p, flags, out);
}

// Round 7
// 3502.472 us; speedup vs baseline: 2.3145x; 1.0952x over previous
//
#include <hip/hip_runtime.h>
#include <hip/hip_bf16.h>

// 2-layer LSTM, B=64, F=128, T=1024, H=512. Output = h_T of layer 1 (64x512 fp32).
// R9: bank-conflict-free staging pad.
// R8b post-mortem: LDS dedup of sc0sc1 h reads = -39% (6270->3836us), confirming
// LLC-congestion theory. But SQ_LDS_BANK_CONFLICT jumped 1.1e7 -> 2.63e8: the
// sA[16][16][32] tile (64B rows) puts all 8 even-l15 lanes of each 16-lane
// ds_read_b128 phase into banks p*4..p*4+3 (l15*16%32=0) -> 8-way conflict on
// every staging read AND write (~24 extra cy each, ~430us of LDS serialization
// on the lgkmcnt->MFMA chain).
// Fix: pad inner dim 32->40 elems (row stride 80B, 16B-aligned). Bank start =
// (l15*20+p*4)%32: l15=0..7 -> {0,20,8,28,16,4,24,12}, all distinct, covering
// all 32 banks exactly 2x per phase = the free 2-way minimum. Same indexing
// fixes the write side. Single-variable change vs R8b.
// Kept: LDS h dedup (R8b), fence-free sc0sc1 coherence (R6b), coalesced publish
// + layer-split slack flags (R7), 4 batch-groups (R5), reg-resident weights (R4).

#define B_ 64
#define F_ 128
#define T_ 1024
#define H_ 512
#define NWG 256
#define APAD 40   // staging inner dim (elements): 80B row stride, conflict-free

typedef __bf16 bf16x8 __attribute__((ext_vector_type(8)));
typedef float f32x4 __attribute__((ext_vector_type(4)));
typedef unsigned u32x4 __attribute__((ext_vector_type(4)));

__device__ __forceinline__ float sigm(float x) { return 1.0f / (1.0f + __expf(-x)); }
__device__ __forceinline__ float tanh_fast(float x) { return 1.0f - 2.0f / (__expf(2.0f * x) + 1.0f); }

// Coherence-point 16B load: bypass L1+L2, read LLC. Callers batch + drain once.
#define GLOAD_SC(dst, base, imm)                                      \
  asm volatile("global_load_dwordx4 %0, %1, off offset:%c2 sc0 sc1"   \
               : "=v"(dst) : "v"(base), "i"(imm))
// Coherence-point 16B store (write-through to LLC); ack drains at vmcnt(0).
#define GSTORE_SC(val, base)                                          \
  asm volatile("global_store_dwordx4 %0, %1, off sc0 sc1"             \
               :: "v"(base), "v"(val) : "memory")

// x (B,F,T) fp32 -> xT (T,B,F) bf16
__global__ __launch_bounds__(256) void transpose_x_kernel(const float* __restrict__ x,
                                                          __bf16* __restrict__ xT) {
  __shared__ float tile[F_][65];
  const int bb = blockIdx.x >> 4;
  const int tt = blockIdx.x & 15;
  const int tid = threadIdx.x;
  const int tl = tid & 63;
  const int f0 = tid >> 6;
  for (int fo = 0; fo < F_; fo += 4) {
    int f = fo + f0;
    tile[f][tl] = x[((size_t)bb * F_ + f) * T_ + tt * 64 + tl];
  }
  __syncthreads();
  const int fw = tid & 127;
  const int tg = tid >> 7;
  for (int to = 0; to < 64; to += 2) {
    int t = to + tg;
    xT[((size_t)(tt * 64 + t) * B_ + bb) * F_ + fw] = (__bf16)tile[fw][t];
  }
}

// arrive: __syncthreads drains each wave's vmcnt (publish stores acked at LLC)
// before tid0 posts the monotone counter.
__device__ __forceinline__ void arrive_flag(unsigned* gfl, int wgl, int tid, unsigned tgt) {
  __syncthreads();
  if (tid == 0)
    __hip_atomic_store(&gfl[wgl], tgt, __ATOMIC_RELAXED, __HIP_MEMORY_SCOPE_AGENT);
}

// wait: wave 0 polls 64 group flags with per-half targets
// (flags[0..32)=L0 WGs, [32..64)=L1 WGs). No acquire fence: h reads are sc0sc1.
__device__ __forceinline__ void wait_split(unsigned* gfl, int tid, unsigned tgtL0, unsigned tgtL1) {
  if (tid < 64) {
    const unsigned tgt = (tid < 32) ? tgtL0 : tgtL1;
    while (__hip_atomic_load(&gfl[tid], __ATOMIC_RELAXED, __HIP_MEMORY_SCOPE_AGENT) < tgt)
      __builtin_amdgcn_s_sleep(1);
  }
  __syncthreads();
}

__global__ __launch_bounds__(256, 1) void lstm_persistent(
    const __bf16* __restrict__ xT,
    const float* __restrict__ Wih0, const float* __restrict__ Whh0,
    const float* __restrict__ bih0, const float* __restrict__ bhh0,
    const float* __restrict__ Wih1, const float* __restrict__ Whh1,
    const float* __restrict__ bih1, const float* __restrict__ bhh1,
    __bf16* h0_pub, __bf16* h1_pub,   // each: [4][B][H] bf16, 4-gen rotation
    unsigned* flags,                   // [4 groups][64] dword counters
    float* __restrict__ out) {
  __shared__ float sG[4][288];                  // per-wave gate slab, stride 72
  __shared__ __align__(16) __bf16 sH[16][24];   // publish transpose tile
  __shared__ __align__(16) __bf16 sA0[16][16][APAD];  // h0 staging [kc][b][col]
  __shared__ __align__(16) __bf16 sA1[16][16][APAD];  // h1 staging (layer-1)

  const int wg   = blockIdx.x;
  const int g    = wg & 3;           // batch group
  const int wgl  = wg >> 2;          // 0..63 within group
  const int tid  = threadIdx.x;
  const int wv   = tid >> 6;
  const int lane = tid & 63;
  const int p    = lane >> 4;        // quad (= gate index for A/C rows)
  const int l15  = lane & 15;
  const int b    = g * 16 + l15;     // global batch
  const int ks   = p * 8;            // k offset inside a 32-chunk
  const int j    = wgl & 31;         // column-group within layer
  const int col4 = j * 16 + wv * 4;  // this wave's 4 h-columns
  const int row  = (l15 >> 2) * H_ + col4 + (l15 & 3);  // A-frag gate row for m=l15
  unsigned* gfl  = flags + (g << 6);
  // publish-store lane mapping (tid<32): 2 lanes per batch, 16B each
  const int pb   = tid >> 1;         // batch within group
  const int phf  = tid & 1;          // which 16B half of the 32B chunk

  if (wgl < 32) {
    // ---------------- layer 0 ----------------
    bf16x8 wh[16], wi[4];
    {
      const float* s = Whh0 + (size_t)row * H_ + ks;
#pragma unroll
      for (int kc = 0; kc < 16; ++kc) {
        bf16x8 a;
#pragma unroll
        for (int jj = 0; jj < 8; ++jj) a[jj] = (__bf16)s[kc * 32 + jj];
        wh[kc] = a;
      }
      const float* si = Wih0 + (size_t)row * F_ + ks;
#pragma unroll
      for (int kc = 0; kc < 4; ++kc) {
        bf16x8 a;
#pragma unroll
        for (int jj = 0; jj < 8; ++jj) a[jj] = (__bf16)si[kc * 32 + jj];
        wi[kc] = a;
      }
    }
    float bq[4];
#pragma unroll
    for (int r = 0; r < 4; ++r) {
      const int grow = p * H_ + col4 + r;
      bq[r] = bih0[grow] + bhh0[grow];
    }

    float c0 = 0.f;
    // x contribution for it=0 (no barrier precedes; xT ready at launch)
    f32x4 accb = {0.f, 0.f, 0.f, 0.f};
    {
      const __bf16* xrow = xT + ((size_t)0 * B_ + b) * F_;
#pragma unroll
      for (int kc = 0; kc < 4; ++kc) {
        bf16x8 xb = *(const bf16x8*)&xrow[kc * 32 + ks];
        accb = __builtin_amdgcn_mfma_f32_16x16x32_bf16(wi[kc], xb, accb, 0, 0, 0);
      }
    }

    for (int it = 0; it < T_; ++it) {
      const __bf16* h0r = h0_pub + ((it + 3) & 3) * (B_ * H_);
      __bf16* h0w = h0_pub + (it & 3) * (B_ * H_);

      // ---- stage h0 slice through LDS (each wave loads k-chunks [4wv,4wv+4)) ----
      {
        const __bf16* src = h0r + (size_t)b * H_ + wv * 128 + ks;
        bf16x8 st0, st1, st2, st3;
        GLOAD_SC(st0, src, 0);
        GLOAD_SC(st1, src, 64);
        GLOAD_SC(st2, src, 128);
        GLOAD_SC(st3, src, 192);
        asm volatile("s_waitcnt vmcnt(0)" ::: "memory");
        __builtin_amdgcn_sched_barrier(0);
        *(bf16x8*)&sA0[wv * 4 + 0][l15][ks] = st0;
        *(bf16x8*)&sA0[wv * 4 + 1][l15][ks] = st1;
        *(bf16x8*)&sA0[wv * 4 + 2][l15][ks] = st2;
        *(bf16x8*)&sA0[wv * 4 + 3][l15][ks] = st3;
      }
      __syncthreads();

      f32x4 acc = {0.f, 0.f, 0.f, 0.f};
#pragma unroll
      for (int kc = 0; kc < 16; ++kc) {
        bf16x8 hb = *(const bf16x8*)&sA0[kc][l15][ks];
        acc = __builtin_amdgcn_mfma_f32_16x16x32_bf16(wh[kc], hb, acc, 0, 0, 0);
      }

#pragma unroll
      for (int r = 0; r < 4; ++r) {
        float v = acc[r] + accb[r] + bq[r];
        sG[wv][p * 72 + r * 16 + l15] = (p == 2) ? tanh_fast(v) : sigm(v);
      }
      // sG slab is per-wave private: lgkmcnt ordering suffices, no barrier
      float gi = sG[wv][0 * 72 + p * 16 + l15];
      float gf = sG[wv][1 * 72 + p * 16 + l15];
      float gg = sG[wv][2 * 72 + p * 16 + l15];
      float go = sG[wv][3 * 72 + p * 16 + l15];
      c0 = gf * c0 + gi * gg;
      float h = go * tanh_fast(c0);

      // coalesced publish: stage WG tile (16 batches x 16 cols) then wave0 stores
      sH[l15][wv * 4 + p] = (__bf16)h;
      __syncthreads();
      if (tid < 32) {
        u32x4 d = *(const u32x4*)&sH[pb][phf * 8];
        __bf16* dst = h0w + (size_t)(g * 16 + pb) * H_ + j * 16 + phf * 8;
        GSTORE_SC(d, dst);
      }
      arrive_flag(gfl, wgl, tid, (unsigned)(it + 1));
      if (it + 1 < T_) {
        // next step's x-GEMM: loads+MFMA hidden under the peer wait
        const __bf16* xrow = xT + ((size_t)(it + 1) * B_ + b) * F_;
        f32x4 nb = {0.f, 0.f, 0.f, 0.f};
#pragma unroll
        for (int kc = 0; kc < 4; ++kc) {
          bf16x8 xb = *(const bf16x8*)&xrow[kc * 32 + ks];
          nb = __builtin_amdgcn_mfma_f32_16x16x32_bf16(wi[kc], xb, nb, 0, 0, 0);
        }
        accb = nb;
        // entering step t=it+1: L0 peers >= t; L1 >= t-2 (4-gen anti-overwrite)
        const unsigned tgtL1 = (it >= 1) ? (unsigned)(it - 1) : 0u;
        wait_split(gfl, tid, (unsigned)(it + 1), tgtL1);
      }
    }
  } else {
    // ---------------- layer 1 ----------------
    bf16x8 wi[16], wh[16];
    {
      const float* s0 = Wih1 + (size_t)row * H_ + ks;
      const float* s1 = Whh1 + (size_t)row * H_ + ks;
#pragma unroll
      for (int kc = 0; kc < 16; ++kc) {
        bf16x8 a, c;
#pragma unroll
        for (int jj = 0; jj < 8; ++jj) {
          a[jj] = (__bf16)s0[kc * 32 + jj];
          c[jj] = (__bf16)s1[kc * 32 + jj];
        }
        wi[kc] = a; wh[kc] = c;
      }
    }
    float bq[4];
#pragma unroll
    for (int r = 0; r < 4; ++r) {
      const int grow = p * H_ + col4 + r;
      bq[r] = bih1[grow] + bhh1[grow];
    }

    float c1 = 0.f;
    arrive_flag(gfl, wgl, tid, 1u);   // "step 0 done" (layer-1 idle that step)
    wait_split(gfl, tid, 1u, 1u);
    for (int it = 1; it <= T_; ++it) {
      const __bf16* h0r = h0_pub + ((it + 3) & 3) * (B_ * H_);
      const __bf16* h1r = h1_pub + ((it + 3) & 3) * (B_ * H_);
      __bf16* h1w = h1_pub + (it & 3) * (B_ * H_);

      // ---- stage h0+h1 slices through LDS ----
      {
        const __bf16* sa = h0r + (size_t)b * H_ + wv * 128 + ks;
        const __bf16* sc = h1r + (size_t)b * H_ + wv * 128 + ks;
        bf16x8 sa0, sa1, sa2, sa3, sc0, sc1_, sc2, sc3;
        GLOAD_SC(sa0, sa, 0);
        GLOAD_SC(sa1, sa, 64);
        GLOAD_SC(sa2, sa, 128);
        GLOAD_SC(sa3, sa, 192);
        GLOAD_SC(sc0, sc, 0);
        GLOAD_SC(sc1_, sc, 64);
        GLOAD_SC(sc2, sc, 128);
        GLOAD_SC(sc3, sc, 192);
        asm volatile("s_waitcnt vmcnt(0)" ::: "memory");
        __builtin_amdgcn_sched_barrier(0);
        *(bf16x8*)&sA0[wv * 4 + 0][l15][ks] = sa0;
        *(bf16x8*)&sA0[wv * 4 + 1][l15][ks] = sa1;
        *(bf16x8*)&sA0[wv * 4 + 2][l15][ks] = sa2;
        *(bf16x8*)&sA0[wv * 4 + 3][l15][ks] = sa3;
        *(bf16x8*)&sA1[wv * 4 + 0][l15][ks] = sc0;
        *(bf16x8*)&sA1[wv * 4 + 1][l15][ks] = sc1_;
        *(bf16x8*)&sA1[wv * 4 + 2][l15][ks] = sc2;
        *(bf16x8*)&sA1[wv * 4 + 3][l15][ks] = sc3;
      }
      __syncthreads();

      f32x4 acca = {0.f, 0.f, 0.f, 0.f};
      f32x4 accc = {0.f, 0.f, 0.f, 0.f};
#pragma unroll
      for (int kc = 0; kc < 16; ++kc) {
        bf16x8 ha = *(const bf16x8*)&sA0[kc][l15][ks];
        bf16x8 hc = *(const bf16x8*)&sA1[kc][l15][ks];
        acca = __builtin_amdgcn_mfma_f32_16x16x32_bf16(wi[kc], ha, acca, 0, 0, 0);
        accc = __builtin_amdgcn_mfma_f32_16x16x32_bf16(wh[kc], hc, accc, 0, 0, 0);
      }
#pragma unroll
      for (int r = 0; r < 4; ++r) {
        float v = acca[r] + accc[r] + bq[r];
        sG[wv][p * 72 + r * 16 + l15] = (p == 2) ? tanh_fast(v) : sigm(v);
      }
      float gi = sG[wv][0 * 72 + p * 16 + l15];
      float gf = sG[wv][1 * 72 + p * 16 + l15];
      float gg = sG[wv][2 * 72 + p * 16 + l15];
      float go = sG[wv][3 * 72 + p * 16 + l15];
      c1 = gf * c1 + gi * gg;
      float h = go * tanh_fast(c1);

      if (it < T_) {
        // coalesced publish of h1 tile
        sH[l15][wv * 4 + p] = (__bf16)h;
        __syncthreads();
        if (tid < 32) {
          u32x4 d = *(const u32x4*)&sH[pb][phf * 8];
          __bf16* dst = h1w + (size_t)(g * 16 + pb) * H_ + j * 16 + phf * 8;
          GSTORE_SC(d, dst);
        }
        arrive_flag(gfl, wgl, tid, (unsigned)(it + 1));
        // entering step it+1: need h0(it) => L0 >= it+1; h1 peers >= it+1
        wait_split(gfl, tid, (unsigned)(it + 1), (unsigned)(it + 1));
      } else {
        out[b * H_ + col4 + p] = h;   // final h1[T-1], fp32
      }
    }
  }
}

// Workspace layout:
//   [0]        flags: 4 groups x 64 x 4B = 1 KiB (16 KiB reserved)
//   [16384]    h0_pub: 4 gens x 64x512x2B = 262144 B
//   [278528]   h1_pub: 262144 B
//   [1 MiB]    xT: 16 MiB
// Zeroed region: [0, 540672).
extern "C" void kernel_launch(void* const* d_in, const int* in_sizes, int n_in,
                              void* d_out, int out_size, void* d_ws, size_t ws_size,
                              hipStream_t stream) {
  const float* x    = (const float*)d_in[0];
  const float* Wih0 = (const float*)d_in[1];
  const float* Whh0 = (const float*)d_in[2];
  const float* bih0 = (const float*)d_in[3];
  const float* bhh0 = (const float*)d_in[4];
  const float* Wih1 = (const float*)d_in[5];
  const float* Whh1 = (const float*)d_in[6];
  const float* bih1 = (const float*)d_in[7];
  const float* bhh1 = (const float*)d_in[8];
  float* out = (float*)d_out;

  char* ws = (char*)d_ws;
  unsigned* flags = (unsigned*)ws;
  __bf16* h0p = (__bf16*)(ws + 16384);
  __bf16* h1p = (__bf16*)(ws + 16384 + 4 * B_ * H_ * 2);
  __bf16* xT  = (__bf16*)(ws + (1 << 20));

  hipMemsetAsync(ws, 0, 16384 + 8 * B_ * H_ * 2, stream);

  transpose_x_kernel<<<dim3(B_ * 16), dim3(256), 0, stream>>>(x, xT);

  lstm_persistent<<<dim3(NWG), dim3(256), 0, stream>>>(
      xT, Wih0, Whh0, bih0, bhh0, Wih1, Whh1, bih1, bhh1,
      h0p, h1p, flags, out);
}